// Round 1
// 8341.853 us; speedup vs baseline: 1.6694x; 1.6694x over previous
//
#include <hip/hip_runtime.h>
#include <hip/hip_bf16.h>

#define BB 512     // batch
#define TT 96      // encoder steps
#define PP 96      // decoder steps
#define EE 321     // input features
#define CC 321     // output channels
#define HH 512     // hidden
#define G4 2048    // 4*H
#define EPAD 352   // 321 padded to 32
#define NFC 384    // fc N pad (64-multiple)

// double-buffered LDS staging: per buffer Xh[128][32] Xl[128][32] Wh[64][32] Wl[64][32] (u16)
#define BUF_SZ 24576
#define XH_OFF 0
#define XL_OFF 8192
#define WH_OFF 16384
#define WL_OFF 20480
#define LSTM_SMEM 49152  // 2 buffers; sG (34816 B) aliases after final barrier

typedef unsigned short u16;
typedef __attribute__((ext_vector_type(8))) short bf16x8;
typedef __attribute__((ext_vector_type(16))) float floatx16;

__device__ __forceinline__ void splitf(float v, u16& h, u16& l){
  __hip_bfloat16 bh = __float2bfloat16(v);
  h = *reinterpret_cast<u16*>(&bh);
  float r = v - __bfloat162float(bh);
  __hip_bfloat16 bl = __float2bfloat16(r);
  l = *reinterpret_cast<u16*>(&bl);
}

// async global->LDS, 16B per lane; LDS dest = wave-uniform base + lane*16 (linear).
__device__ __forceinline__ void gload16(const void* g, void* l){
  __builtin_amdgcn_global_load_lds((const __attribute__((address_space(1))) void*)g,
                                   (__attribute__((address_space(3))) void*)l, 16, 0, 0);
}

// ---------- prep: split fp32 [rows][cols] -> bf16 hi/lo [rowspad][colspad] ----------
__global__ void cvt_split(const float* __restrict__ src, u16* __restrict__ hi, u16* __restrict__ lo,
                          int rows, int cols, int rowspad, int colspad){
  int total = rowspad * colspad;
  for (int idx = blockIdx.x * blockDim.x + threadIdx.x; idx < total; idx += gridDim.x * blockDim.x){
    int r = idx / colspad, cc = idx - r * colspad;
    float v = (r < rows && cc < cols) ? src[(size_t)r * cols + cc] : 0.f;
    u16 h, l; splitf(v, h, l);
    hi[idx] = h; lo[idx] = l;
  }
}

__global__ void cvt_bias(const float* __restrict__ b1, const float* __restrict__ b2,
                         float* __restrict__ dst, int n, int npad){
  for (int i = blockIdx.x * blockDim.x + threadIdx.x; i < npad; i += gridDim.x * blockDim.x){
    float v = 0.f;
    if (i < n){ v = b1[i]; if (b2) v += b2[i]; }
    dst[i] = v;
  }
}

// inp split from x_enc[:, T-1, :], pad zeroed
__global__ void init_inp(const float* __restrict__ x_enc, u16* __restrict__ inph, u16* __restrict__ inpl){
  int total = BB * EPAD;
  for (int idx = blockIdx.x * blockDim.x + threadIdx.x; idx < total; idx += gridDim.x * blockDim.x){
    int b = idx / EPAD, j = idx - b * EPAD;
    float v = (j < EE) ? x_enc[(size_t)b * TT * EE + (size_t)(TT - 1) * EE + j] : 0.f;
    u16 h, l; splitf(v, h, l);
    inph[idx] = h; inpl[idx] = l;
  }
}

// pre-split x_enc [B][T][E] -> [T][B][EPAD] hi/lo (once; removes f32+splitf from encoder hot loop)
__global__ void split_xenc(const float* __restrict__ x, u16* __restrict__ xh, u16* __restrict__ xl){
  const int total = TT * BB * EPAD;
  for (int idx = blockIdx.x * blockDim.x + threadIdx.x; idx < total; idx += gridDim.x * blockDim.x){
    int e = idx % EPAD;
    int rest = idx / EPAD;
    int b = rest % BB;
    int t = rest / BB;
    float v = (e < EE) ? x[((size_t)b * TT + t) * EE + e] : 0.f;
    u16 h, l; splitf(v, h, l);
    xh[idx] = h; xl[idx] = l;
  }
}

// ---------- LSTM cell body: tile M=128 batch x N=64 gate-cols (16 units x 4 gates) ----------
// 256 thr = 4 waves. Split-bf16: P ~= Xh@Wh + Xh@Wl + Xl@Wh via mfma_f32_32x32x16_bf16.
// Pipeline: global_load_lds double-buffer, counted vmcnt(6) across raw barriers (T3-min).
// LDS rows are 64B (32 u16); 16B slots XOR-swizzled by (row>>1)&3 on BOTH write(source) and read.
__device__ __forceinline__ void lstm_body(
    char* smem, int bx,
    const u16* __restrict__ Xh, const u16* __restrict__ Xl, int K1pad,
    const u16* __restrict__ Wih_h, const u16* __restrict__ Wih_l, // [2048][K1pad]
    const u16* __restrict__ Whh_h, const u16* __restrict__ Whh_l, // [2048][512]
    const float* __restrict__ bias,
    const u16* __restrict__ Hph, const u16* __restrict__ Hpl, // prev h split [512][512]
    u16* __restrict__ Hnh, u16* __restrict__ Hnl,             // next h split
    float* __restrict__ cst)                                  // c state fp32 [512][512]
{
  float (*sG)[68] = (float (*)[68])(smem);   // aliases staging; used only after final barrier

  const int tid  = threadIdx.x;
  const int lane = tid & 63;
  const int wid  = tid >> 6;
  const int wm = wid >> 1, wn = wid & 1;
  const int m0 = (bx >> 5) * 128;
  const int u0 = (bx & 31) * 16;

  floatx16 acc0 = {0.f,0.f,0.f,0.f,0.f,0.f,0.f,0.f,0.f,0.f,0.f,0.f,0.f,0.f,0.f,0.f};
  floatx16 acc1 = {0.f,0.f,0.f,0.f,0.f,0.f,0.f,0.f,0.f,0.f,0.f,0.f,0.f,0.f,0.f,0.f};

  // MFMA fragment addressing
  const int ml    = lane & 31;
  const int thalf = lane >> 5;           // k-half
  const int a0r = wm * 64 + ml;          // A rows (X)
  const int a1r = a0r + 32;
  const int brw = wn * 32 + ml;          // B row (W)
  const int xa  = (a0r >> 1) & 3;        // read-side XOR (same for a1r: +32 keeps (r>>1)&3)
  const int xb  = (brw >> 1) & 3;

  // staging: wave w stages X rows [w*32,w*32+32) (2 ops/array), W rows [w*16,(w+1)*16) (1 op/array)
  const int sl  = lane & 3;
  const int rq  = lane >> 2;             // 0..15
  const int rx0 = wid * 32 + rq;
  const int rw  = wid * 16 + rq;
  const int sgx = (sl ^ ((rx0 >> 1) & 3)) << 4;   // source-slot pre-swizzle (bytes)
  const int sgw = (sl ^ ((rw  >> 1) & 3)) << 4;
  const size_t gxr0 = (size_t)(m0 + rx0);
  const size_t gxr1 = gxr0 + 16;
  const size_t gwr  = (size_t)wid * HH + u0 + rq; // gate-row remap: LDS row r -> (r>>4)*HH+u0+(r&15)
  const int oX = wid * 32 * 64;
  const int oW = wid * 16 * 64;

  const int nch1 = K1pad >> 5;
  const int ncht = nch1 + (HH >> 5);

  auto stage = [&](int ch){
    const bool p1 = ch < nch1;
    const int k0 = (p1 ? ch : ch - nch1) << 5;
    const u16* xh = p1 ? Xh : Hph;
    const u16* xl = p1 ? Xl : Hpl;
    const u16* wh = p1 ? Wih_h : Whh_h;
    const u16* wl = p1 ? Wih_l : Whh_l;
    const size_t Kp = p1 ? (size_t)K1pad : (size_t)HH;
    char* b = smem + (ch & 1) * BUF_SZ;
    gload16((const char*)(xh + gxr0 * Kp + k0) + sgx, b + XH_OFF + oX);
    gload16((const char*)(xh + gxr1 * Kp + k0) + sgx, b + XH_OFF + oX + 1024);
    gload16((const char*)(xl + gxr0 * Kp + k0) + sgx, b + XL_OFF + oX);
    gload16((const char*)(xl + gxr1 * Kp + k0) + sgx, b + XL_OFF + oX + 1024);
    gload16((const char*)(wh + gwr  * Kp + k0) + sgw, b + WH_OFF + oW);
    gload16((const char*)(wl + gwr  * Kp + k0) + sgw, b + WL_OFF + oW);
  };

  stage(0);
  for (int ch = 0; ch < ncht; ++ch){
    if (ch + 1 < ncht) stage(ch + 1);            // prefetch next chunk into other buffer
    __builtin_amdgcn_sched_barrier(0);
    if (ch + 1 < ncht) { asm volatile("s_waitcnt vmcnt(6)" ::: "memory"); }  // this chunk's 6 done
    else               { asm volatile("s_waitcnt vmcnt(0)" ::: "memory"); }
    __builtin_amdgcn_s_barrier();                // all waves: chunk ch resident
    __builtin_amdgcn_sched_barrier(0);
    const char* bufc = smem + (ch & 1) * BUF_SZ;
    #pragma unroll
    for (int kk2 = 0; kk2 < 2; ++kk2){
      const int t0 = kk2 * 2 + thalf;            // 16B slot index 0..3
      bf16x8 ah0 = *(const bf16x8*)(bufc + XH_OFF + a0r * 64 + ((t0 ^ xa) << 4));
      bf16x8 al0 = *(const bf16x8*)(bufc + XL_OFF + a0r * 64 + ((t0 ^ xa) << 4));
      bf16x8 ah1 = *(const bf16x8*)(bufc + XH_OFF + a1r * 64 + ((t0 ^ xa) << 4));
      bf16x8 al1 = *(const bf16x8*)(bufc + XL_OFF + a1r * 64 + ((t0 ^ xa) << 4));
      bf16x8 bh  = *(const bf16x8*)(bufc + WH_OFF + brw * 64 + ((t0 ^ xb) << 4));
      bf16x8 bl  = *(const bf16x8*)(bufc + WL_OFF + brw * 64 + ((t0 ^ xb) << 4));
      acc0 = __builtin_amdgcn_mfma_f32_32x32x16_bf16(ah0, bh, acc0, 0, 0, 0);
      acc0 = __builtin_amdgcn_mfma_f32_32x32x16_bf16(ah0, bl, acc0, 0, 0, 0);
      acc0 = __builtin_amdgcn_mfma_f32_32x32x16_bf16(al0, bh, acc0, 0, 0, 0);
      acc1 = __builtin_amdgcn_mfma_f32_32x32x16_bf16(ah1, bh, acc1, 0, 0, 0);
      acc1 = __builtin_amdgcn_mfma_f32_32x32x16_bf16(ah1, bl, acc1, 0, 0, 0);
      acc1 = __builtin_amdgcn_mfma_f32_32x32x16_bf16(al1, bh, acc1, 0, 0, 0);
    }
    __builtin_amdgcn_sched_barrier(0);
    asm volatile("s_waitcnt lgkmcnt(0)" ::: "memory");
    __builtin_amdgcn_s_barrier();                // all waves done reading this buffer
    __builtin_amdgcn_sched_barrier(0);
  }
  __syncthreads();  // bulletproof fence before sG aliases the staging buffers

  // ---- epilogue: gate exchange via LDS (aliased), cell update, split-write h ----
  #pragma unroll
  for (int r = 0; r < 16; ++r){
    const int mm = (r & 3) + 8 * (r >> 2) + 4 * thalf;  // C/D row map
    sG[wm * 64 + mm][wn * 32 + ml]      = acc0[r];
    sG[wm * 64 + 32 + mm][wn * 32 + ml] = acc1[r];
  }
  __syncthreads();
  for (int e = tid; e < 2048; e += 256){
    const int m = e >> 4, u = e & 15;
    const int gj = u0 + u;
    const float gi = sG[m][u]      + bias[gj];
    const float gf = sG[m][16 + u] + bias[HH + gj];
    const float gg = sG[m][32 + u] + bias[2 * HH + gj];
    const float go = sG[m][48 + u] + bias[3 * HH + gj];
    const float si = 1.f / (1.f + expf(-gi));
    const float sf = 1.f / (1.f + expf(-gf));
    const float so = 1.f / (1.f + expf(-go));
    const size_t sidx = (size_t)(m0 + m) * HH + gj;
    const float cn = sf * cst[sidx] + si * tanhf(gg);
    const float hn = so * tanhf(cn);
    cst[sidx] = cn;
    u16 hh, hl; splitf(hn, hh, hl);
    Hnh[sidx] = hh; Hnl[sidx] = hl;
  }
}

__global__ __launch_bounds__(256) void lstm_one(
    const u16* Xh, const u16* Xl, int K1pad,
    const u16* Wih_h, const u16* Wih_l, const u16* Whh_h, const u16* Whh_l,
    const float* bias, const u16* Hph, const u16* Hpl,
    u16* Hnh, u16* Hnl, float* cst)
{
  extern __shared__ char smem[];
  lstm_body(smem, blockIdx.x, Xh, Xl, K1pad,
            Wih_h, Wih_l, Whh_h, Whh_l, bias, Hph, Hpl, Hnh, Hnl, cst);
}

// Fused encoder step: blocks [0,128) = cell0 step t, [128,256) = cell1 step t-1.
__global__ __launch_bounds__(256) void lstm_pair(
    int act0, const u16* X0h, const u16* X0l,
    const u16* W0ih_h, const u16* W0ih_l, const u16* W0hh_h, const u16* W0hh_l,
    const float* b0, const u16* H0ph, const u16* H0pl, u16* H0nh, u16* H0nl, float* c0,
    int act1, const u16* X1h, const u16* X1l,
    const u16* W1ih_h, const u16* W1ih_l, const u16* W1hh_h, const u16* W1hh_l,
    const float* b1, const u16* H1ph, const u16* H1pl, u16* H1nh, u16* H1nl, float* c1)
{
  extern __shared__ char smem[];
  const int half = blockIdx.x >> 7;
  const int bx   = blockIdx.x & 127;
  if (half == 0 ? !act0 : !act1) return;
  lstm_body(smem, bx,
            half ? X1h : X0h, half ? X1l : X0l, half ? HH : EPAD,
            half ? W1ih_h : W0ih_h, half ? W1ih_l : W0ih_l,
            half ? W1hh_h : W0hh_h, half ? W1hh_l : W0hh_l,
            half ? b1 : b0,
            half ? H1ph : H0ph, half ? H1pl : H0pl,
            half ? H1nh : H0nh, half ? H1nl : H0nl,
            half ? c1 : c0);
}

// ---------- FC head (split-bf16 MFMA, same pipelined staging): out = h1 @ fcW^T + fcb ----------
__global__ __launch_bounds__(256) void fc_mfma(
    const u16* __restrict__ Hh, const u16* __restrict__ Hl,       // [512][512]
    const u16* __restrict__ Wh, const u16* __restrict__ Wl,       // [384][512]
    const float* __restrict__ bfc,                                // [384]
    float* __restrict__ out, u16* __restrict__ inph, u16* __restrict__ inpl, int p)
{
  extern __shared__ char smem[];
  const int tid = threadIdx.x, lane = tid & 63, wid = tid >> 6;
  const int wm = wid >> 1, wn = wid & 1;
  const int m0 = blockIdx.x * 128;
  const int n0 = blockIdx.y * 64;

  floatx16 acc0 = {0.f,0.f,0.f,0.f,0.f,0.f,0.f,0.f,0.f,0.f,0.f,0.f,0.f,0.f,0.f,0.f};
  floatx16 acc1 = {0.f,0.f,0.f,0.f,0.f,0.f,0.f,0.f,0.f,0.f,0.f,0.f,0.f,0.f,0.f,0.f};

  const int ml    = lane & 31;
  const int thalf = lane >> 5;
  const int a0r = wm * 64 + ml;
  const int a1r = a0r + 32;
  const int brw = wn * 32 + ml;
  const int xa  = (a0r >> 1) & 3;
  const int xb  = (brw >> 1) & 3;

  const int sl  = lane & 3;
  const int rq  = lane >> 2;
  const int rx0 = wid * 32 + rq;
  const int rw  = wid * 16 + rq;
  const int sgx = (sl ^ ((rx0 >> 1) & 3)) << 4;
  const int sgw = (sl ^ ((rw  >> 1) & 3)) << 4;
  const size_t gxr0 = (size_t)(m0 + rx0);
  const size_t gxr1 = gxr0 + 16;
  const size_t gwr  = (size_t)(n0 + rw);
  const int oX = wid * 32 * 64;
  const int oW = wid * 16 * 64;

  auto stage = [&](int ch){
    const int k0 = ch << 5;
    char* b = smem + (ch & 1) * BUF_SZ;
    gload16((const char*)(Hh + gxr0 * HH + k0) + sgx, b + XH_OFF + oX);
    gload16((const char*)(Hh + gxr1 * HH + k0) + sgx, b + XH_OFF + oX + 1024);
    gload16((const char*)(Hl + gxr0 * HH + k0) + sgx, b + XL_OFF + oX);
    gload16((const char*)(Hl + gxr1 * HH + k0) + sgx, b + XL_OFF + oX + 1024);
    gload16((const char*)(Wh + gwr  * HH + k0) + sgw, b + WH_OFF + oW);
    gload16((const char*)(Wl + gwr  * HH + k0) + sgw, b + WL_OFF + oW);
  };

  stage(0);
  for (int ch = 0; ch < 16; ++ch){
    if (ch + 1 < 16) stage(ch + 1);
    __builtin_amdgcn_sched_barrier(0);
    if (ch + 1 < 16) { asm volatile("s_waitcnt vmcnt(6)" ::: "memory"); }
    else             { asm volatile("s_waitcnt vmcnt(0)" ::: "memory"); }
    __builtin_amdgcn_s_barrier();
    __builtin_amdgcn_sched_barrier(0);
    const char* bufc = smem + (ch & 1) * BUF_SZ;
    #pragma unroll
    for (int kk2 = 0; kk2 < 2; ++kk2){
      const int t0 = kk2 * 2 + thalf;
      bf16x8 ah0 = *(const bf16x8*)(bufc + XH_OFF + a0r * 64 + ((t0 ^ xa) << 4));
      bf16x8 al0 = *(const bf16x8*)(bufc + XL_OFF + a0r * 64 + ((t0 ^ xa) << 4));
      bf16x8 ah1 = *(const bf16x8*)(bufc + XH_OFF + a1r * 64 + ((t0 ^ xa) << 4));
      bf16x8 al1 = *(const bf16x8*)(bufc + XL_OFF + a1r * 64 + ((t0 ^ xa) << 4));
      bf16x8 bh  = *(const bf16x8*)(bufc + WH_OFF + brw * 64 + ((t0 ^ xb) << 4));
      bf16x8 bl  = *(const bf16x8*)(bufc + WL_OFF + brw * 64 + ((t0 ^ xb) << 4));
      acc0 = __builtin_amdgcn_mfma_f32_32x32x16_bf16(ah0, bh, acc0, 0, 0, 0);
      acc0 = __builtin_amdgcn_mfma_f32_32x32x16_bf16(ah0, bl, acc0, 0, 0, 0);
      acc0 = __builtin_amdgcn_mfma_f32_32x32x16_bf16(al0, bh, acc0, 0, 0, 0);
      acc1 = __builtin_amdgcn_mfma_f32_32x32x16_bf16(ah1, bh, acc1, 0, 0, 0);
      acc1 = __builtin_amdgcn_mfma_f32_32x32x16_bf16(ah1, bl, acc1, 0, 0, 0);
      acc1 = __builtin_amdgcn_mfma_f32_32x32x16_bf16(al1, bh, acc1, 0, 0, 0);
    }
    __builtin_amdgcn_sched_barrier(0);
    asm volatile("s_waitcnt lgkmcnt(0)" ::: "memory");
    __builtin_amdgcn_s_barrier();
    __builtin_amdgcn_sched_barrier(0);
  }

  const int n = n0 + wn * 32 + ml;
  if (n < CC){
    const float bv = bfc[n];
    #pragma unroll
    for (int r = 0; r < 16; ++r){
      const int mm = (r & 3) + 8 * (r >> 2) + 4 * thalf;
      {
        const int b = m0 + wm * 64 + mm;
        const float v = acc0[r] + bv;
        out[(size_t)b * PP * CC + (size_t)p * CC + n] = v;
        u16 hh, hl; splitf(v, hh, hl);
        inph[(size_t)b * EPAD + n] = hh; inpl[(size_t)b * EPAD + n] = hl;
      }
      {
        const int b = m0 + wm * 64 + 32 + mm;
        const float v = acc1[r] + bv;
        out[(size_t)b * PP * CC + (size_t)p * CC + n] = v;
        u16 hh, hl; splitf(v, hh, hl);
        inph[(size_t)b * EPAD + n] = hh; inpl[(size_t)b * EPAD + n] = hl;
      }
    }
  }
}

extern "C" void kernel_launch(void* const* d_in, const int* in_sizes, int n_in,
                              void* d_out, int out_size, void* d_ws, size_t ws_size,
                              hipStream_t stream) {
  const float* x_enc  = (const float*)d_in[0];
  const float* e_Wih0 = (const float*)d_in[4];
  const float* e_Whh0 = (const float*)d_in[5];
  const float* e_bih0 = (const float*)d_in[6];
  const float* e_bhh0 = (const float*)d_in[7];
  const float* e_Wih1 = (const float*)d_in[8];
  const float* e_Whh1 = (const float*)d_in[9];
  const float* e_bih1 = (const float*)d_in[10];
  const float* e_bhh1 = (const float*)d_in[11];
  const float* d_Wih0 = (const float*)d_in[12];
  const float* d_Whh0 = (const float*)d_in[13];
  const float* d_bih0 = (const float*)d_in[14];
  const float* d_bhh0 = (const float*)d_in[15];
  const float* d_Wih1 = (const float*)d_in[16];
  const float* d_Whh1 = (const float*)d_in[17];
  const float* d_bih1 = (const float*)d_in[18];
  const float* d_bhh1 = (const float*)d_in[19];
  const float* fc_W   = (const float*)d_in[20];
  const float* fc_b   = (const float*)d_in[21];

  char* base = (char*)d_ws;
  size_t off = 0;
  auto alloc_us = [&](size_t n){ u16* p = (u16*)(base + off); off += ((n * 2 + 15) & ~(size_t)15); return p; };
  auto alloc_f  = [&](size_t n){ float* p = (float*)(base + off); off += ((n * 4 + 15) & ~(size_t)15); return p; };

  u16 *We0ih_h = alloc_us((size_t)G4 * EPAD), *We0ih_l = alloc_us((size_t)G4 * EPAD);
  u16 *We0hh_h = alloc_us((size_t)G4 * HH),   *We0hh_l = alloc_us((size_t)G4 * HH);
  u16 *We1ih_h = alloc_us((size_t)G4 * HH),   *We1ih_l = alloc_us((size_t)G4 * HH);
  u16 *We1hh_h = alloc_us((size_t)G4 * HH),   *We1hh_l = alloc_us((size_t)G4 * HH);
  u16 *Wd0ih_h = alloc_us((size_t)G4 * EPAD), *Wd0ih_l = alloc_us((size_t)G4 * EPAD);
  u16 *Wd0hh_h = alloc_us((size_t)G4 * HH),   *Wd0hh_l = alloc_us((size_t)G4 * HH);
  u16 *Wd1ih_h = alloc_us((size_t)G4 * HH),   *Wd1ih_l = alloc_us((size_t)G4 * HH);
  u16 *Wd1hh_h = alloc_us((size_t)G4 * HH),   *Wd1hh_l = alloc_us((size_t)G4 * HH);
  u16 *Wfc_h   = alloc_us((size_t)NFC * HH),  *Wfc_l   = alloc_us((size_t)NFC * HH);
  float* be0 = alloc_f(G4);
  float* be1 = alloc_f(G4);
  float* bd0 = alloc_f(G4);
  float* bd1 = alloc_f(G4);
  float* bfc = alloc_f(NFC);
  // zero-init region: h0[0], h1[0] (hi+lo) then c0, c1 — one memset covers all
  u16* h0h[2]; u16* h0l[2]; u16* h1h[2]; u16* h1l[2];
  h0h[0] = alloc_us((size_t)BB * HH); h0l[0] = alloc_us((size_t)BB * HH);
  h1h[0] = alloc_us((size_t)BB * HH); h1l[0] = alloc_us((size_t)BB * HH);
  float* c0 = alloc_f((size_t)BB * HH);
  float* c1 = alloc_f((size_t)BB * HH);
  h0h[1] = alloc_us((size_t)BB * HH); h0l[1] = alloc_us((size_t)BB * HH);
  h1h[1] = alloc_us((size_t)BB * HH); h1l[1] = alloc_us((size_t)BB * HH);
  u16* inph = alloc_us((size_t)BB * EPAD);
  u16* inpl = alloc_us((size_t)BB * EPAD);
  u16* Xench = alloc_us((size_t)TT * BB * EPAD);
  u16* Xencl = alloc_us((size_t)TT * BB * EPAD);

  // prep (every launch; ws re-poisoned by harness)
  cvt_split<<<512, 256, 0, stream>>>(e_Wih0, We0ih_h, We0ih_l, G4, EE, G4, EPAD);
  cvt_split<<<512, 256, 0, stream>>>(e_Whh0, We0hh_h, We0hh_l, G4, HH, G4, HH);
  cvt_split<<<512, 256, 0, stream>>>(e_Wih1, We1ih_h, We1ih_l, G4, HH, G4, HH);
  cvt_split<<<512, 256, 0, stream>>>(e_Whh1, We1hh_h, We1hh_l, G4, HH, G4, HH);
  cvt_split<<<512, 256, 0, stream>>>(d_Wih0, Wd0ih_h, Wd0ih_l, G4, EE, G4, EPAD);
  cvt_split<<<512, 256, 0, stream>>>(d_Whh0, Wd0hh_h, Wd0hh_l, G4, HH, G4, HH);
  cvt_split<<<512, 256, 0, stream>>>(d_Wih1, Wd1ih_h, Wd1ih_l, G4, HH, G4, HH);
  cvt_split<<<512, 256, 0, stream>>>(d_Whh1, Wd1hh_h, Wd1hh_l, G4, HH, G4, HH);
  cvt_split<<<512, 256, 0, stream>>>(fc_W,   Wfc_h,   Wfc_l,   CC, HH, NFC, HH);
  cvt_bias<<<8, 256, 0, stream>>>(e_bih0, e_bhh0, be0, G4, G4);
  cvt_bias<<<8, 256, 0, stream>>>(e_bih1, e_bhh1, be1, G4, G4);
  cvt_bias<<<8, 256, 0, stream>>>(d_bih0, d_bhh0, bd0, G4, G4);
  cvt_bias<<<8, 256, 0, stream>>>(d_bih1, d_bhh1, bd1, G4, G4);
  cvt_bias<<<2, 256, 0, stream>>>(fc_b, nullptr, bfc, CC, NFC);
  hipMemsetAsync(h0h[0], 0, (size_t)4 * BB * HH * sizeof(u16) + (size_t)2 * BB * HH * sizeof(float), stream);
  init_inp<<<512, 256, 0, stream>>>(x_enc, inph, inpl);
  split_xenc<<<4096, 256, 0, stream>>>(x_enc, Xench, Xencl);

  // encoder: fused pipeline, iteration t runs cell0(t) and cell1(t-1)
  for (int t = 0; t <= TT; ++t){
    const int rd = t & 1, wrp = (t + 1) & 1;
    const size_t ts = (size_t)(t < TT ? t : 0) * BB * EPAD;
    lstm_pair<<<256, 256, LSTM_SMEM, stream>>>(
        (t < TT) ? 1 : 0, Xench + ts, Xencl + ts,
        We0ih_h, We0ih_l, We0hh_h, We0hh_l, be0,
        h0h[rd], h0l[rd], h0h[wrp], h0l[wrp], c0,
        (t > 0) ? 1 : 0, h0h[rd], h0l[rd],
        We1ih_h, We1ih_l, We1hh_h, We1hh_l, be1,
        h1h[wrp], h1l[wrp], h1h[rd], h1l[rd], c1);
  }
  // encoder finals land at parity 0 for both h0 and h1

  // decoder
  float* out = (float*)d_out;
  for (int p = 0; p < PP; ++p){
    const int rd = p & 1, wrp = (p + 1) & 1;
    lstm_one<<<128, 256, LSTM_SMEM, stream>>>(
        inph, inpl, EPAD,
        Wd0ih_h, Wd0ih_l, Wd0hh_h, Wd0hh_l, bd0,
        h0h[rd], h0l[rd], h0h[wrp], h0l[wrp], c0);
    lstm_one<<<128, 256, LSTM_SMEM, stream>>>(
        h0h[wrp], h0l[wrp], HH,
        Wd1ih_h, Wd1ih_l, Wd1hh_h, Wd1hh_l, bd1,
        h1h[rd], h1l[rd], h1h[wrp], h1l[wrp], c1);
    fc_mfma<<<dim3(4, 6), 256, LSTM_SMEM, stream>>>(
        h1h[wrp], h1l[wrp], Wfc_h, Wfc_l, bfc, out, inph, inpl, p);
  }
}